// Round 1
// baseline (184.812 us; speedup 1.0000x reference)
//
#include <hip/hip_runtime.h>

// RoDAlignMax: features [4,256,64,64] f32, rois [2048,5] -> out [2048,256,9,9] f32
// Grid samples are exactly (7i, 7j): bilinear degenerates to a gather.
// Kernel 1: gather G[b][p][c] (p = i*10+j, 100 points) = F[b,c,7i,7j]  (400 KB, L2-resident)
// Kernel 2: per (roi, channel-half) block: masked 10x10 -> 2x2/s1 maxpool -> 9x9,
//           LDS transpose for coalesced stores.

#define NB 4
#define NC 256
#define HW 64
#define NR 2048

__global__ __launch_bounds__(256) void rod_gather(const float* __restrict__ F,
                                                  float* __restrict__ G) {
    int idx = blockIdx.x * 256 + threadIdx.x;      // < 4*100*256 = 102400
    int c = idx & 255;
    int t = idx >> 8;                              // b*100 + p
    int p = t % 100;
    int b = t / 100;
    int i = p / 10, j = p - i * 10;
    // F[((b*256 + c)*64 + 7i)*64 + 7j]
    G[idx] = F[((b * NC + c) << 12) + i * 448 + j * 7];
}

__global__ __launch_bounds__(128) void rod_main(const float* __restrict__ G,
                                                const float* __restrict__ rois,
                                                float* __restrict__ out) {
    __shared__ float lds[128 * 83];                // stride 83 (odd) -> conflict-free writes
    const int tid  = threadIdx.x;
    const int r    = blockIdx.x >> 1;
    const int half = blockIdx.x & 1;
    const int c    = half * 128 + tid;

    const float x1 = rois[r * 5 + 1] * 0.25f;
    const float y1 = rois[r * 5 + 2] * 0.25f;
    const float x2 = rois[r * 5 + 3] * 0.25f;
    const float y2 = rois[r * 5 + 4] * 0.25f;
    const int  b   = (int)rois[r * 5 + 0];

    bool inw[10], inh[10];
    #pragma unroll
    for (int j = 0; j < 10; ++j) {
        float s = 7.0f * (float)j;                 // exact grid coordinate
        inw[j] = (s >= x1) && (s <= x2);
        inh[j] = (s >= y1) && (s <= y2);
    }

    // G[b][p][c]: stride 256 floats per p; lanes (consecutive c) coalesce each load.
    const float* gb = G + (size_t)b * 100 * NC + c;

    float vprev[10];
    #pragma unroll
    for (int j = 0; j < 10; ++j) {
        float g = gb[j * NC];
        vprev[j] = (inh[0] && inw[j]) ? 0.0f : g;
    }
    #pragma unroll
    for (int i = 1; i < 10; ++i) {
        float vcur[10];
        #pragma unroll
        for (int j = 0; j < 10; ++j) {
            float g = gb[(i * 10 + j) * NC];
            vcur[j] = (inh[i] && inw[j]) ? 0.0f : g;
        }
        float rm[10];
        #pragma unroll
        for (int j = 0; j < 10; ++j) rm[j] = fmaxf(vprev[j], vcur[j]);
        #pragma unroll
        for (int j = 0; j < 9; ++j)
            lds[tid * 83 + (i - 1) * 9 + j] = fmaxf(rm[j], rm[j + 1]);
        #pragma unroll
        for (int j = 0; j < 10; ++j) vprev[j] = vcur[j];
    }
    __syncthreads();

    // Cooperative coalesced write-back: el = c_local*81 + p, LDS addr = el + 2*(el/81).
    float* dst = out + (size_t)r * 20736 + half * 10368;
    #pragma unroll 9
    for (int k = 0; k < 81; ++k) {
        int el = tid + (k << 7);                   // 0..10367, each exactly once
        int cc = (int)((unsigned)el / 81u);        // magic-mul div
        dst[el] = lds[el + cc * 2];
    }
}

extern "C" void kernel_launch(void* const* d_in, const int* in_sizes, int n_in,
                              void* d_out, int out_size, void* d_ws, size_t ws_size,
                              hipStream_t stream) {
    const float* F    = (const float*)d_in[0];   // 4*256*64*64
    const float* rois = (const float*)d_in[1];   // 2048*5
    float*       out  = (float*)d_out;           // 2048*256*9*9
    float*       G    = (float*)d_ws;            // 4*100*256 floats = 409600 B

    rod_gather<<<dim3(400), dim3(256), 0, stream>>>(F, G);
    rod_main<<<dim3(NR * 2), dim3(128), 0, stream>>>(G, rois, out);
}